// Round 3
// baseline (260.476 us; speedup 1.0000x reference)
//
#include <hip/hip_runtime.h>
#include <hip/hip_cooperative_groups.h>

namespace cg = cooperative_groups;

#define BB 16384
#define KK 64
#define DD 128
#define SEG 128          // rows per covariance work-item (single 128-row stage)
#define MAXITEMS 192     // sum_k ceil(cnt_k/SEG) <= 128 + 63 = 191
#define NRB 4            // reduce slabs per cluster
#define RSLAB 4096       // elements per reduce slab
#define RBLKS (KK * NRB) // 256 reducer blocks

typedef __attribute__((ext_vector_type(8))) short bf16x8;
typedef __attribute__((ext_vector_type(4))) float f32x4;

__device__ __forceinline__ unsigned int packbf2(float a, float b) {
    unsigned ua = __float_as_uint(a);
    unsigned ub = __float_as_uint(b);
    ua = (ua + 0x7FFFu + ((ua >> 16) & 1u)) >> 16;   // RNE f32->bf16
    ub = (ub + 0x7FFFu + ((ub >> 16) & 1u)) >> 16;
    return ua | (ub << 16);
}

// ---------------------------------------------------------------------------
// K1: tiled GEMM. Block = 64 rows x 64 clusters, K=128. 512 threads/block
// (2 waves/SIMD). dist = |x|^2 - 2 x.c + |c|^2 ; |x|^2 cancels in softmax
// AND argmin. Emits per-block cluster histogram bhist[b][k].
// ---------------------------------------------------------------------------
__global__ __launch_bounds__(512) void k_rows(
    const float* __restrict__ x, const float* __restrict__ centers,
    float* __restrict__ log_resp, int* __restrict__ assign,
    int* __restrict__ bhist)
{
    __shared__ float xs[64][132];    // X tile, +4 pad
    __shared__ float ct[DD][66];     // centers transposed [d][k]
    __shared__ float cn2[KK];
    __shared__ int   lh[KK];

    const int tid = threadIdx.x;
    const int row0 = blockIdx.x * 64;

    if (tid < KK) lh[tid] = 0;

    for (int g = tid; g < 64 * 32; g += 512) {
        int r = g >> 5, c4 = g & 31;
        float4 v = ((const float4*)(x + (size_t)(row0 + r) * DD))[c4];
        *(float4*)&xs[r][c4 * 4] = v;
    }
    for (int g = tid; g < KK * 32; g += 512) {
        int k = g >> 5, c4 = g & 31;
        float4 v = ((const float4*)(centers + (size_t)k * DD))[c4];
        ct[c4 * 4 + 0][k] = v.x;
        ct[c4 * 4 + 1][k] = v.y;
        ct[c4 * 4 + 2][k] = v.z;
        ct[c4 * 4 + 3][k] = v.w;
    }
    __syncthreads();
    if (tid < KK) {
        float s = 0.f;
        for (int d = 0; d < DD; ++d) { float c = ct[d][tid]; s = fmaf(c, c, s); }
        cn2[tid] = s;
    }
    __syncthreads();

    const int tr = tid >> 5;         // 0..15 row-groups of 4 rows
    const int tc = tid & 31;
    const int k0 = tc * 2, k1 = k0 + 1;

    float acc0[4], acc1[4];
    #pragma unroll
    for (int i = 0; i < 4; ++i) { acc0[i] = 0.f; acc1[i] = 0.f; }

    for (int d = 0; d < DD; d += 4) {
        float2 b0 = *(const float2*)&ct[d + 0][k0];
        float2 b1 = *(const float2*)&ct[d + 1][k0];
        float2 b2 = *(const float2*)&ct[d + 2][k0];
        float2 b3 = *(const float2*)&ct[d + 3][k0];
        #pragma unroll
        for (int i = 0; i < 4; ++i) {
            float4 a = *(const float4*)&xs[tr * 4 + i][d];
            acc0[i] = fmaf(a.x, b0.x, acc0[i]);
            acc1[i] = fmaf(a.x, b0.y, acc1[i]);
            acc0[i] = fmaf(a.y, b1.x, acc0[i]);
            acc1[i] = fmaf(a.y, b1.y, acc1[i]);
            acc0[i] = fmaf(a.z, b2.x, acc0[i]);
            acc1[i] = fmaf(a.z, b2.y, acc1[i]);
            acc0[i] = fmaf(a.w, b3.x, acc0[i]);
            acc1[i] = fmaf(a.w, b3.y, acc1[i]);
        }
    }

    const float cn0 = 0.5f * cn2[k0], cn1 = 0.5f * cn2[k1];
    #pragma unroll
    for (int i = 0; i < 4; ++i) {
        int row = row0 + tr * 4 + i;
        float v0 = acc0[i] - cn0;
        float v1 = acc1[i] - cn1;
        float m; int idx;
        if (v1 > v0) { m = v1; idx = k1; } else { m = v0; idx = k0; }
        #pragma unroll
        for (int off = 1; off < 32; off <<= 1) {
            float ov = __shfl_xor(m, off);
            int   oi = __shfl_xor(idx, off);
            if (ov > m || (ov == m && oi < idx)) { m = ov; idx = oi; }
        }
        float s = expf(v0 - m) + expf(v1 - m);
        #pragma unroll
        for (int off = 1; off < 32; off <<= 1) s += __shfl_xor(s, off);
        float ls = logf(s);
        float lr0 = fmaxf(v0 - m - ls, -18.4206807f);  // log(1e-8)
        float lr1 = fmaxf(v1 - m - ls, -18.4206807f);
        *(float2*)&log_resp[(size_t)row * KK + k0] = make_float2(lr0, lr1);
        if (tc == 0) {
            assign[row] = idx;
            atomicAdd(&lh[idx], 1);
        }
    }
    __syncthreads();
    if (tid < KK) bhist[blockIdx.x * KK + tid] = lh[tid];   // coalesced 256B
}

// ---------------------------------------------------------------------------
// K_REST: cooperative fusion of the former K2 (scatter) + K3 (MFMA items) +
// K4 (parallel slab reduce). Grid 256x256, ALL blocks co-resident (67.6 KB
// dynamic LDS -> 2 blocks/CU max). Phase bodies are verbatim R1 code; the
// two grid.sync()s replace two kernel-launch full drains. R2 lesson: the
// per-cluster reduce must keep K4's 256-block parallelism (cluster sizes are
// heavily skewed; a single-block finisher was a 57us serial tail).
// ---------------------------------------------------------------------------
struct SmemA {     // scatter phase
    int ph_tot[4][KK], ph_pre[4][KK];
    int cnt_s[KK], pre_s[KK], base_s[KK], cur_s[KK];
    int iof[KK + 1];
};
struct SmemB {     // seg phase
    int rows_s[128];
    unsigned int XT[DD][68];   // XT[d][j] = bf16 pair rows (2j,2j+1)
};
struct SmemC {     // reduce phase
    float red[4][RSLAB];       // 64 KB
    float mu_s[DD], emp_s[DD];
    float emp2[2][DD];
    float rds[4], ros[4], rmm[4];
    int is_last;
};
union SmemU { SmemA a; SmemB b; SmemC c; };

__global__ __launch_bounds__(256) void k_rest(
    const float* __restrict__ x, const float* __restrict__ centers,
    const int* __restrict__ assign, const int* __restrict__ bhist,
    int* __restrict__ sorted, float* __restrict__ cw,
    int4* __restrict__ items, int* __restrict__ item_count,
    int* __restrict__ ist, int* __restrict__ ien,
    float* __restrict__ part, float* __restrict__ emp_part,
    float2* __restrict__ spart, int* __restrict__ counter,
    float* __restrict__ outscalars)
{
    extern __shared__ unsigned char smem_raw[];
    SmemU& smem = *reinterpret_cast<SmemU*>(smem_raw);
    cg::grid_group grid = cg::this_grid();

    const int tid = threadIdx.x;

    // ---------------- Phase A: counting-sort scatter (ex-K2) ---------------
    {
        const int b = blockIdx.x;
        const int t = tid & 63, q = tid >> 6;

        int tot = 0, pre = 0;
        const int bb0 = q * 64;
        for (int bb = bb0; bb < bb0 + 64; ++bb) {
            int v = bhist[bb * KK + t];          // lanes consecutive: coalesced
            tot += v;
            if (bb < b) pre += v;
        }
        smem.a.ph_tot[q][t] = tot; smem.a.ph_pre[q][t] = pre;
        __syncthreads();

        if (tid < KK) {
            smem.a.cnt_s[tid] = smem.a.ph_tot[0][tid] + smem.a.ph_tot[1][tid]
                              + smem.a.ph_tot[2][tid] + smem.a.ph_tot[3][tid];
            smem.a.pre_s[tid] = smem.a.ph_pre[0][tid] + smem.a.ph_pre[1][tid]
                              + smem.a.ph_pre[2][tid] + smem.a.ph_pre[3][tid];
            smem.a.cur_s[tid] = 0;
        }
        __syncthreads();
        if (tid == 0) {
            int base = 0;
            for (int k = 0; k < KK; ++k) { smem.a.base_s[k] = base; base += smem.a.cnt_s[k]; }
        }
        __syncthreads();

        if (tid < 64) {
            int r = b * 64 + tid;
            int a = assign[r];
            int p = smem.a.base_s[a] + smem.a.pre_s[a] + atomicAdd(&smem.a.cur_s[a], 1);
            sorted[p] = r;                       // intra-cluster order: don't care
        }

        if (b == 0) {
            if (tid < KK) cw[tid] = (float)smem.a.cnt_s[tid];
            if (tid == KK) *counter = 0;
            if (tid == 0) {
                int ic = 0;
                for (int k = 0; k < KK; ++k) {
                    smem.a.iof[k] = ic;
                    ic += (smem.a.cnt_s[k] + SEG - 1) / SEG;
                }
                smem.a.iof[KK] = ic;
                *item_count = ic;
            }
            __syncthreads();                     // block-uniform branch: legal
            if (tid < KK) {
                const int k = tid, c = smem.a.cnt_s[k], io = smem.a.iof[k];
                ist[k] = io;
                ien[k] = smem.a.iof[k + 1];
                int j = 0;
                for (int s = 0; s < c; s += SEG, ++j) {
                    int4 it; it.x = k; it.y = smem.a.base_s[k] + s;
                    it.z = min(SEG, c - s); it.w = 0;
                    items[io + j] = it;
                }
            }
        }
    }

    __threadfence();
    grid.sync();

    // ---------------- Phase B: per-item Sxx via MFMA (ex-K3) ---------------
    if ((int)blockIdx.x < *item_count) {
        int4 it = items[blockIdx.x];
        const int gstart = it.y, len = it.z;   // len in [1,128]

        const int w = tid >> 6, lane = tid & 63;
        const int c4 = lane & 15, q = lane >> 4;

        f32x4 acc[2][8];
        #pragma unroll
        for (int h = 0; h < 2; ++h)
            #pragma unroll
            for (int nt = 0; nt < 8; ++nt)
                acc[h][nt] = (f32x4){0.f, 0.f, 0.f, 0.f};

        if (tid < len) smem.b.rows_s[tid] = sorted[gstart + tid];
        __syncthreads();

        // stage: wave w owns dims [w*32, w*32+32); lane owns row pair
        {
            const int r0 = 2 * lane, r1 = 2 * lane + 1;
            const int d0 = w * 32;
            const float* p0 = x + (size_t)smem.b.rows_s[r0 < len ? r0 : 0] * DD + d0;
            const float* p1 = x + (size_t)smem.b.rows_s[r1 < len ? r1 : 0] * DD + d0;
            #pragma unroll
            for (int i = 0; i < 8; ++i) {
                float4 a = make_float4(0.f, 0.f, 0.f, 0.f);
                float4 b = make_float4(0.f, 0.f, 0.f, 0.f);
                if (r0 < len) a = *(const float4*)(p0 + 4 * i);
                if (r1 < len) b = *(const float4*)(p1 + 4 * i);
                smem.b.XT[d0 + 4 * i + 0][lane] = packbf2(a.x, b.x);
                smem.b.XT[d0 + 4 * i + 1][lane] = packbf2(a.y, b.y);
                smem.b.XT[d0 + 4 * i + 2][lane] = packbf2(a.z, b.z);
                smem.b.XT[d0 + 4 * i + 3][lane] = packbf2(a.w, b.w);
            }
        }
        __syncthreads();

        // column sums (f32 from the bf16 data): thread d < 128
        float colsum = 0.f;
        if (tid < DD) {
            #pragma unroll
            for (int j4 = 0; j4 < 16; ++j4) {
                uint4 v = *(const uint4*)&smem.b.XT[tid][j4 * 4];
                colsum += __uint_as_float(v.x << 16) + __uint_as_float(v.x & 0xFFFF0000u);
                colsum += __uint_as_float(v.y << 16) + __uint_as_float(v.y & 0xFFFF0000u);
                colsum += __uint_as_float(v.z << 16) + __uint_as_float(v.z & 0xFFFF0000u);
                colsum += __uint_as_float(v.w << 16) + __uint_as_float(v.w & 0xFFFF0000u);
            }
            emp_part[blockIdx.x * DD + tid] = colsum;   // non-atomic
        }

        // MFMA: wave w owns m-tiles {2w, 2w+1} x n-tiles 0..7
        #pragma unroll
        for (int c = 0; c < 4; ++c) {          // K chunks of 32 rows
            const int ku = c * 16 + q * 4;     // u32 index: k0 = c*32 + q*8
            bf16x8 a0 = *(const bf16x8*)&smem.b.XT[(2 * w + 0) * 16 + c4][ku];
            bf16x8 a1 = *(const bf16x8*)&smem.b.XT[(2 * w + 1) * 16 + c4][ku];
            #pragma unroll
            for (int nt = 0; nt < 8; ++nt) {
                bf16x8 b = *(const bf16x8*)&smem.b.XT[nt * 16 + c4][ku];
                acc[0][nt] = __builtin_amdgcn_mfma_f32_16x16x32_bf16(a0, b, acc[0][nt], 0, 0, 0);
                acc[1][nt] = __builtin_amdgcn_mfma_f32_16x16x32_bf16(a1, b, acc[1][nt], 0, 0, 0);
            }
        }

        // C/D layout: col = lane&15, row = quad*4 + reg  [m89/m91 verified]
        float* pb = part + (size_t)blockIdx.x * (DD * DD);
        #pragma unroll
        for (int h = 0; h < 2; ++h) {
            const int m0 = (2 * w + h) * 16 + q * 4;
            #pragma unroll
            for (int nt = 0; nt < 8; ++nt) {
                const int n = nt * 16 + c4;
                pb[(m0 + 0) * DD + n] = acc[h][nt].x;
                pb[(m0 + 1) * DD + n] = acc[h][nt].y;
                pb[(m0 + 2) * DD + n] = acc[h][nt].z;
                pb[(m0 + 3) * DD + n] = acc[h][nt].w;
            }
        }
    }

    __threadfence();
    grid.sync();

    // ---------------- Phase C: parallel slab reduce + MSE (ex-K4) ----------
    {
        const int k = blockIdx.x >> 2;
        const int p = blockIdx.x & 3;
        const int i0 = ist[k], i1 = ien[k];
        const int w = tid >> 6, lane = tid & 63;
        const float wgt = cw[k];
        const float inv = 1.0f / (wgt + 1e-7f);

        // emp = sum over items of emp_part (2 thread-groups x 2 chains)
        {
            const int dh = tid & 127, hf = tid >> 7;
            float e0 = 0.f, e1 = 0.f;
            int it = i0 + hf;
            for (; it + 2 < i1; it += 4) {
                e0 += emp_part[it * DD + dh];
                e1 += emp_part[(it + 2) * DD + dh];
            }
            if (it < i1) e0 += emp_part[it * DD + dh];
            smem.c.emp2[hf][dh] = e0 + e1;
        }
        __syncthreads();
        if (tid < DD) {
            float e = smem.c.emp2[0][tid] + smem.c.emp2[1][tid];
            smem.c.emp_s[tid] = e;
            smem.c.mu_s[tid] = e * inv;
        }

        float4 acc[16];
        #pragma unroll
        for (int c = 0; c < 16; ++c) acc[c] = make_float4(0.f, 0.f, 0.f, 0.f);

        const int base = p * RSLAB;
        for (int it = i0 + w; it < i1; it += 4) {
            const float* pb = part + (size_t)it * (DD * DD) + base;
            #pragma unroll
            for (int c = 0; c < 16; ++c) {
                float4 v = *(const float4*)&pb[c * 256 + lane * 4];
                acc[c].x += v.x; acc[c].y += v.y; acc[c].z += v.z; acc[c].w += v.w;
            }
        }
        #pragma unroll
        for (int c = 0; c < 16; ++c)
            *(float4*)&smem.c.red[w][c * 256 + lane * 4] = acc[c];
        __syncthreads();   // also orders mu_s/emp_s writes

        float ds = 0.f, os = 0.f, mm = 0.f;
        #pragma unroll
        for (int jj = 0; jj < 16; ++jj) {
            int el = jj * 256 + tid;               // stride-1 across lanes
            float sx = smem.c.red[0][el] + smem.c.red[1][el]
                     + smem.c.red[2][el] + smem.c.red[3][el];
            int gel = base + el;
            int d = gel >> 7, e = gel & 127;
            float ctv = sx - smem.c.mu_s[d] * smem.c.emp_s[e]
                      - smem.c.emp_s[d] * smem.c.mu_s[e]
                      + wgt * smem.c.mu_s[d] * smem.c.mu_s[e];
            float v = ctv * inv;
            if (d == e) { float t = v - 1.f; ds += t * t; }
            else        { os += v * v; }
        }
        if (p == 0 && tid < DD) {
            float t = smem.c.mu_s[tid] - centers[k * DD + tid];
            mm = t * t;
        }

        #pragma unroll
        for (int off = 32; off > 0; off >>= 1) {
            ds += __shfl_down(ds, off);
            os += __shfl_down(os, off);
            mm += __shfl_down(mm, off);
        }
        if (lane == 0) { smem.c.rds[w] = ds; smem.c.ros[w] = os; smem.c.rmm[w] = mm; }
        __syncthreads();
        if (tid == 0) {
            float DS = smem.c.rds[0] + smem.c.rds[1] + smem.c.rds[2] + smem.c.rds[3];
            float OS = smem.c.ros[0] + smem.c.ros[1] + smem.c.ros[2] + smem.c.ros[3];
            float MM = smem.c.rmm[0] + smem.c.rmm[1] + smem.c.rmm[2] + smem.c.rmm[3];
            const float bd = (float)BB * (float)DD;
            float2 mine;
            mine.x = wgt * MM / bd;
            mine.y = wgt * DS / bd + wgt * OS / (bd * (float)(DD - 1));
            spart[blockIdx.x] = mine;
            __threadfence();                       // release partial
            int old = atomicAdd(counter, 1);
            smem.c.is_last = (old == RBLKS - 1);
        }
        __syncthreads();
        if (smem.c.is_last) {
            __threadfence();                       // acquire all partials
            float2 v = (tid < RBLKS) ? spart[tid] : make_float2(0.f, 0.f);
            float a = v.x, b = v.y;
            #pragma unroll
            for (int off = 32; off > 0; off >>= 1) {
                a += __shfl_down(a, off);
                b += __shfl_down(b, off);
            }
            __shared__ float ra[4], rb[4];
            if (lane == 0) { ra[w] = a; rb[w] = b; }
            __syncthreads();
            if (tid == 0) {
                outscalars[0] = ra[0] + ra[1] + ra[2] + ra[3];
                outscalars[1] = rb[0] + rb[1] + rb[2] + rb[3];
            }
        }
    }
}

// ---------------------------------------------------------------------------
extern "C" void kernel_launch(void* const* d_in, const int* in_sizes, int n_in,
                              void* d_out, int out_size, void* d_ws, size_t ws_size,
                              hipStream_t stream) {
    const float* x = (const float*)d_in[0];
    const float* centers = (const float*)d_in[1];
    float* out = (float*)d_out;
    float* outscalars = out + (size_t)BB * KK;

    char* ws = (char*)d_ws;
    size_t off = 0;
    float*  part     = (float*)(ws + off); off += (size_t)MAXITEMS * DD * DD * 4; // 12.6 MB
    float*  emp_part = (float*)(ws + off); off += (size_t)MAXITEMS * DD * 4;      // 96 KB
    int*    sorted   = (int*)  (ws + off); off += BB * 4;                         // 64 KB
    int*    assign   = (int*)  (ws + off); off += BB * 4;                         // 64 KB
    int*    bhist    = (int*)  (ws + off); off += 256 * KK * 4;                   // 64 KB
    int4*   items    = (int4*) (ws + off); off += 256 * 16;                       // 4 KB
    float*  cw       = (float*)(ws + off); off += 256;
    int*    itemcnt  = (int*)  (ws + off); off += 256;
    int*    ist      = (int*)  (ws + off); off += 256;
    int*    ien      = (int*)  (ws + off); off += 256;
    float2* spart    = (float2*)(ws + off); off += RBLKS * 8;                     // 2 KB
    int*    counter  = (int*)  (ws + off); off += 256;

    k_rows<<<256, 512, 0, stream>>>(x, centers, out, assign, bhist);

    void* args[] = {
        (void*)&x, (void*)&centers, (void*)&assign, (void*)&bhist,
        (void*)&sorted, (void*)&cw, (void*)&items, (void*)&itemcnt,
        (void*)&ist, (void*)&ien, (void*)&part, (void*)&emp_part,
        (void*)&spart, (void*)&counter, (void*)&outscalars
    };
    hipLaunchCooperativeKernel((const void*)k_rest, dim3(256), dim3(256),
                               args, (unsigned int)sizeof(SmemU), stream);
}

// Round 4
// 158.904 us; speedup vs baseline: 1.6392x; 1.6392x over previous
//
#include <hip/hip_runtime.h>

#define BB 16384
#define KK 64
#define DD 128
#define SEG 128          // rows per covariance work-item (single 128-row stage)
#define MAXITEMS 192     // sum_k ceil(cnt_k/SEG) <= 128 + 63 = 191
#define NRB 4            // reduce slabs per cluster
#define RSLAB 4096       // elements per reduce slab
#define RBLKS (KK * NRB) // 256 reducer blocks

typedef __attribute__((ext_vector_type(8))) short bf16x8;
typedef __attribute__((ext_vector_type(4))) float f32x4;

__device__ __forceinline__ unsigned int packbf2(float a, float b) {
    unsigned ua = __float_as_uint(a);
    unsigned ub = __float_as_uint(b);
    ua = (ua + 0x7FFFu + ((ua >> 16) & 1u)) >> 16;   // RNE f32->bf16
    ub = (ub + 0x7FFFu + ((ub >> 16) & 1u)) >> 16;
    return ua | (ub << 16);
}

// ---------------------------------------------------------------------------
// K1: tiled GEMM. Block = 64 rows x 64 clusters, K=128. 512 threads/block
// (2 waves/SIMD — R1-verified). dist = |x|^2 - 2 x.c + |c|^2 ; |x|^2 cancels
// in softmax AND argmin. Emits per-block cluster histogram bhist[b][k].
// ---------------------------------------------------------------------------
__global__ __launch_bounds__(512) void k_rows(
    const float* __restrict__ x, const float* __restrict__ centers,
    float* __restrict__ log_resp, int* __restrict__ assign,
    int* __restrict__ bhist)
{
    __shared__ float xs[64][132];    // X tile, +4 pad
    __shared__ float ct[DD][66];     // centers transposed [d][k]
    __shared__ float cn2[KK];
    __shared__ int   lh[KK];

    const int tid = threadIdx.x;
    const int row0 = blockIdx.x * 64;

    if (tid < KK) lh[tid] = 0;

    for (int g = tid; g < 64 * 32; g += 512) {
        int r = g >> 5, c4 = g & 31;
        float4 v = ((const float4*)(x + (size_t)(row0 + r) * DD))[c4];
        *(float4*)&xs[r][c4 * 4] = v;
    }
    for (int g = tid; g < KK * 32; g += 512) {
        int k = g >> 5, c4 = g & 31;
        float4 v = ((const float4*)(centers + (size_t)k * DD))[c4];
        ct[c4 * 4 + 0][k] = v.x;
        ct[c4 * 4 + 1][k] = v.y;
        ct[c4 * 4 + 2][k] = v.z;
        ct[c4 * 4 + 3][k] = v.w;
    }
    __syncthreads();
    if (tid < KK) {
        float s = 0.f;
        for (int d = 0; d < DD; ++d) { float c = ct[d][tid]; s = fmaf(c, c, s); }
        cn2[tid] = s;
    }
    __syncthreads();

    const int tr = tid >> 5;         // 0..15 row-groups of 4 rows
    const int tc = tid & 31;
    const int k0 = tc * 2, k1 = k0 + 1;

    float acc0[4], acc1[4];
    #pragma unroll
    for (int i = 0; i < 4; ++i) { acc0[i] = 0.f; acc1[i] = 0.f; }

    for (int d = 0; d < DD; d += 4) {
        float2 b0 = *(const float2*)&ct[d + 0][k0];
        float2 b1 = *(const float2*)&ct[d + 1][k0];
        float2 b2 = *(const float2*)&ct[d + 2][k0];
        float2 b3 = *(const float2*)&ct[d + 3][k0];
        #pragma unroll
        for (int i = 0; i < 4; ++i) {
            float4 a = *(const float4*)&xs[tr * 4 + i][d];
            acc0[i] = fmaf(a.x, b0.x, acc0[i]);
            acc1[i] = fmaf(a.x, b0.y, acc1[i]);
            acc0[i] = fmaf(a.y, b1.x, acc0[i]);
            acc1[i] = fmaf(a.y, b1.y, acc1[i]);
            acc0[i] = fmaf(a.z, b2.x, acc0[i]);
            acc1[i] = fmaf(a.z, b2.y, acc1[i]);
            acc0[i] = fmaf(a.w, b3.x, acc0[i]);
            acc1[i] = fmaf(a.w, b3.y, acc1[i]);
        }
    }

    const float cn0 = 0.5f * cn2[k0], cn1 = 0.5f * cn2[k1];
    #pragma unroll
    for (int i = 0; i < 4; ++i) {
        int row = row0 + tr * 4 + i;
        float v0 = acc0[i] - cn0;
        float v1 = acc1[i] - cn1;
        float m; int idx;
        if (v1 > v0) { m = v1; idx = k1; } else { m = v0; idx = k0; }
        #pragma unroll
        for (int off = 1; off < 32; off <<= 1) {
            float ov = __shfl_xor(m, off);
            int   oi = __shfl_xor(idx, off);
            if (ov > m || (ov == m && oi < idx)) { m = ov; idx = oi; }
        }
        float s = expf(v0 - m) + expf(v1 - m);
        #pragma unroll
        for (int off = 1; off < 32; off <<= 1) s += __shfl_xor(s, off);
        float ls = logf(s);
        float lr0 = fmaxf(v0 - m - ls, -18.4206807f);  // log(1e-8)
        float lr1 = fmaxf(v1 - m - ls, -18.4206807f);
        *(float2*)&log_resp[(size_t)row * KK + k0] = make_float2(lr0, lr1);
        if (tc == 0) {
            assign[row] = idx;
            atomicAdd(&lh[idx], 1);
        }
    }
    __syncthreads();
    if (tid < KK) bhist[blockIdx.x * KK + tid] = lh[tid];   // coalesced 256B
}

// ---------------------------------------------------------------------------
// K2 (256 blocks): parallel counting-sort scatter (R1-verified). Block 0
// emits items (SEG=128) / ist / ien / itemcnt / cw, zeroes arrived[] and the
// final-reduction counter (workspace is poisoned each iteration).
// ---------------------------------------------------------------------------
__global__ __launch_bounds__(256) void k_scat(
    const int* __restrict__ assign, const int* __restrict__ bhist,
    int* __restrict__ sorted, float* __restrict__ cw,
    int4* __restrict__ items, int* __restrict__ item_count,
    int* __restrict__ ist, int* __restrict__ ien,
    int* __restrict__ arrived, int* __restrict__ counter)
{
    __shared__ int ph_tot[4][KK], ph_pre[4][KK];
    __shared__ int cnt_s[KK], pre_s[KK], base_s[KK], cur_s[KK];
    __shared__ int iof[KK + 1];

    const int tid = threadIdx.x;
    const int b = blockIdx.x;
    const int t = tid & 63, q = tid >> 6;

    int tot = 0, pre = 0;
    const int bb0 = q * 64;
    for (int bb = bb0; bb < bb0 + 64; ++bb) {
        int v = bhist[bb * KK + t];          // lanes consecutive: coalesced
        tot += v;
        if (bb < b) pre += v;
    }
    ph_tot[q][t] = tot; ph_pre[q][t] = pre;
    __syncthreads();

    if (tid < KK) {
        cnt_s[tid] = ph_tot[0][tid] + ph_tot[1][tid] + ph_tot[2][tid] + ph_tot[3][tid];
        pre_s[tid] = ph_pre[0][tid] + ph_pre[1][tid] + ph_pre[2][tid] + ph_pre[3][tid];
        cur_s[tid] = 0;
    }
    __syncthreads();
    if (tid == 0) {
        int base = 0;
        for (int k = 0; k < KK; ++k) { base_s[k] = base; base += cnt_s[k]; }
    }
    __syncthreads();

    if (tid < 64) {
        int r = b * 64 + tid;
        int a = assign[r];
        int p = base_s[a] + pre_s[a] + atomicAdd(&cur_s[a], 1);
        sorted[p] = r;                       // intra-cluster order: don't care
    }

    if (b == 0) {
        if (tid < KK) {
            cw[tid] = (float)cnt_s[tid];
            arrived[tid] = 0;
        }
        if (tid == KK) *counter = 0;
        if (tid == 0) {
            int ic = 0;
            for (int k = 0; k < KK; ++k) {
                iof[k] = ic;
                ic += (cnt_s[k] + SEG - 1) / SEG;
            }
            iof[KK] = ic;
            *item_count = ic;
        }
        __syncthreads();                     // block-uniform branch: legal
        if (tid < KK) {
            const int k = tid, c = cnt_s[k], io = iof[k];
            ist[k] = io;
            ien[k] = iof[k + 1];
            int j = 0;
            for (int s = 0; s < c; s += SEG, ++j) {
                int4 it; it.x = k; it.y = base_s[k] + s;
                it.z = min(SEG, c - s); it.w = 0;
                items[io + j] = it;
            }
        }
    }
}

// ---------------------------------------------------------------------------
// K3' (448 blocks, one launch): blocks [0,192) are PRODUCERS (R1 k_seg body:
// per-item Sxx via MFMA, publish part/emp_part, release via arrived[k]++).
// Blocks [192,448) are REDUCERS: (k,p) = slab p of cluster k; spin-wait
// arrived[k]==nitems(k) (device-scope atomic poll), then run the R1 k_redfinal
// body VERBATIM — full 256-block parallel reduce (R2 lesson), but starting
// per-cluster as soon as that cluster's items finish, and without a
// kernel-launch drain (R3 lesson: no cooperative launch).
// Deadlock-free: 448 blocks x 66.3KB LDS -> 2 blocks/CU capacity = 512 >= 448,
// all co-resident regardless of dispatch order.
// ---------------------------------------------------------------------------
struct PSmem {     // producer
    int rows_s[128];
    unsigned int XT[DD][68];   // XT[d][j] = bf16 pair rows (2j,2j+1)
};
struct RSmem {     // reducer
    float red[4][RSLAB];       // 64 KB
    float mu_s[DD], emp_s[DD];
    float emp2[2][DD];
    float rds[4], ros[4], rmm[4];
    float ra[4], rb[4];
    int is_last;
};
union USmem { PSmem pr; RSmem rd; };

__global__ __launch_bounds__(256) void k_segred(
    const float* __restrict__ x, const int* __restrict__ sorted,
    const int4* __restrict__ items, const int* __restrict__ item_count,
    const int* __restrict__ ist, const int* __restrict__ ien,
    const float* __restrict__ cw, const float* __restrict__ centers,
    float* __restrict__ part, float* __restrict__ emp_part,
    int* arrived, float2* __restrict__ spart,
    int* __restrict__ counter, float* __restrict__ outscalars)
{
    __shared__ USmem sm;
    const int tid = threadIdx.x;
    const int w = tid >> 6, lane = tid & 63;

    if ((int)blockIdx.x < MAXITEMS) {
        // ========================= PRODUCER ================================
        if ((int)blockIdx.x >= *item_count) return;
        int4 it = items[blockIdx.x];
        const int k = it.x, gstart = it.y, len = it.z;   // len in [1,128]

        const int c4 = lane & 15, q = lane >> 4;

        f32x4 acc[2][8];
        #pragma unroll
        for (int h = 0; h < 2; ++h)
            #pragma unroll
            for (int nt = 0; nt < 8; ++nt)
                acc[h][nt] = (f32x4){0.f, 0.f, 0.f, 0.f};

        if (tid < len) sm.pr.rows_s[tid] = sorted[gstart + tid];
        __syncthreads();

        // stage: wave w owns dims [w*32, w*32+32); lane owns row pair
        {
            const int r0 = 2 * lane, r1 = 2 * lane + 1;
            const int d0 = w * 32;
            const float* p0 = x + (size_t)sm.pr.rows_s[r0 < len ? r0 : 0] * DD + d0;
            const float* p1 = x + (size_t)sm.pr.rows_s[r1 < len ? r1 : 0] * DD + d0;
            #pragma unroll
            for (int i = 0; i < 8; ++i) {
                float4 a = make_float4(0.f, 0.f, 0.f, 0.f);
                float4 b = make_float4(0.f, 0.f, 0.f, 0.f);
                if (r0 < len) a = *(const float4*)(p0 + 4 * i);
                if (r1 < len) b = *(const float4*)(p1 + 4 * i);
                sm.pr.XT[d0 + 4 * i + 0][lane] = packbf2(a.x, b.x);
                sm.pr.XT[d0 + 4 * i + 1][lane] = packbf2(a.y, b.y);
                sm.pr.XT[d0 + 4 * i + 2][lane] = packbf2(a.z, b.z);
                sm.pr.XT[d0 + 4 * i + 3][lane] = packbf2(a.w, b.w);
            }
        }
        __syncthreads();

        // column sums (f32 from the bf16 data): thread d < 128
        if (tid < DD) {
            float colsum = 0.f;
            #pragma unroll
            for (int j4 = 0; j4 < 16; ++j4) {
                uint4 v = *(const uint4*)&sm.pr.XT[tid][j4 * 4];
                colsum += __uint_as_float(v.x << 16) + __uint_as_float(v.x & 0xFFFF0000u);
                colsum += __uint_as_float(v.y << 16) + __uint_as_float(v.y & 0xFFFF0000u);
                colsum += __uint_as_float(v.z << 16) + __uint_as_float(v.z & 0xFFFF0000u);
                colsum += __uint_as_float(v.w << 16) + __uint_as_float(v.w & 0xFFFF0000u);
            }
            emp_part[blockIdx.x * DD + tid] = colsum;   // non-atomic
        }

        // MFMA: wave w owns m-tiles {2w, 2w+1} x n-tiles 0..7
        #pragma unroll
        for (int c = 0; c < 4; ++c) {          // K chunks of 32 rows
            const int ku = c * 16 + q * 4;     // u32 index: k0 = c*32 + q*8
            bf16x8 a0 = *(const bf16x8*)&sm.pr.XT[(2 * w + 0) * 16 + c4][ku];
            bf16x8 a1 = *(const bf16x8*)&sm.pr.XT[(2 * w + 1) * 16 + c4][ku];
            #pragma unroll
            for (int nt = 0; nt < 8; ++nt) {
                bf16x8 b = *(const bf16x8*)&sm.pr.XT[nt * 16 + c4][ku];
                acc[0][nt] = __builtin_amdgcn_mfma_f32_16x16x32_bf16(a0, b, acc[0][nt], 0, 0, 0);
                acc[1][nt] = __builtin_amdgcn_mfma_f32_16x16x32_bf16(a1, b, acc[1][nt], 0, 0, 0);
            }
        }

        // C/D layout: col = lane&15, row = quad*4 + reg  [m89/m91 verified]
        float* pb = part + (size_t)blockIdx.x * (DD * DD);
        #pragma unroll
        for (int h = 0; h < 2; ++h) {
            const int m0 = (2 * w + h) * 16 + q * 4;
            #pragma unroll
            for (int nt = 0; nt < 8; ++nt) {
                const int n = nt * 16 + c4;
                pb[(m0 + 0) * DD + n] = acc[h][nt].x;
                pb[(m0 + 1) * DD + n] = acc[h][nt].y;
                pb[(m0 + 2) * DD + n] = acc[h][nt].z;
                pb[(m0 + 3) * DD + n] = acc[h][nt].w;
            }
        }

        __threadfence();                 // each thread releases its own writes
        __syncthreads();
        if (tid == 0) atomicAdd(&arrived[k], 1);
        return;
    }

    // =========================== REDUCER ===================================
    const int j = (int)blockIdx.x - MAXITEMS;   // 0..255
    const int k = j >> 2;
    const int p = j & 3;
    const int i0 = ist[k], i1 = ien[k];
    const int nitems = i1 - i0;
    const float wgt = cw[k];
    const float inv = 1.0f / (wgt + 1e-7f);

    if (tid == 0 && nitems > 0) {
        while (atomicAdd(&arrived[k], 0) < nitems)   // device-scope poll
            __builtin_amdgcn_s_sleep(8);
    }
    __syncthreads();
    __threadfence();                     // acquire all items' part writes

    // emp = sum over items of emp_part (2 thread-groups x 2 chains)
    {
        const int dh = tid & 127, hf = tid >> 7;
        float e0 = 0.f, e1 = 0.f;
        int it = i0 + hf;
        for (; it + 2 < i1; it += 4) {
            e0 += emp_part[it * DD + dh];
            e1 += emp_part[(it + 2) * DD + dh];
        }
        if (it < i1) e0 += emp_part[it * DD + dh];
        sm.rd.emp2[hf][dh] = e0 + e1;
    }
    __syncthreads();
    if (tid < DD) {
        float e = sm.rd.emp2[0][tid] + sm.rd.emp2[1][tid];
        sm.rd.emp_s[tid] = e;
        sm.rd.mu_s[tid] = e * inv;
    }

    float4 acc[16];
    #pragma unroll
    for (int c = 0; c < 16; ++c) acc[c] = make_float4(0.f, 0.f, 0.f, 0.f);

    const int base = p * RSLAB;
    for (int it = i0 + w; it < i1; it += 4) {
        const float* pb = part + (size_t)it * (DD * DD) + base;
        #pragma unroll
        for (int c = 0; c < 16; ++c) {
            float4 v = *(const float4*)&pb[c * 256 + lane * 4];
            acc[c].x += v.x; acc[c].y += v.y; acc[c].z += v.z; acc[c].w += v.w;
        }
    }
    #pragma unroll
    for (int c = 0; c < 16; ++c)
        *(float4*)&sm.rd.red[w][c * 256 + lane * 4] = acc[c];
    __syncthreads();   // also orders mu_s/emp_s writes

    float ds = 0.f, os = 0.f, mm = 0.f;
    #pragma unroll
    for (int jj = 0; jj < 16; ++jj) {
        int el = jj * 256 + tid;               // stride-1 across lanes
        float sx = sm.rd.red[0][el] + sm.rd.red[1][el]
                 + sm.rd.red[2][el] + sm.rd.red[3][el];
        int gel = base + el;
        int d = gel >> 7, e = gel & 127;
        float ctv = sx - sm.rd.mu_s[d] * sm.rd.emp_s[e]
                  - sm.rd.emp_s[d] * sm.rd.mu_s[e]
                  + wgt * sm.rd.mu_s[d] * sm.rd.mu_s[e];
        float v = ctv * inv;
        if (d == e) { float t = v - 1.f; ds += t * t; }
        else        { os += v * v; }
    }
    if (p == 0 && tid < DD) {
        float t = sm.rd.mu_s[tid] - centers[k * DD + tid];
        mm = t * t;
    }

    #pragma unroll
    for (int off = 32; off > 0; off >>= 1) {
        ds += __shfl_down(ds, off);
        os += __shfl_down(os, off);
        mm += __shfl_down(mm, off);
    }
    if (lane == 0) { sm.rd.rds[w] = ds; sm.rd.ros[w] = os; sm.rd.rmm[w] = mm; }
    __syncthreads();
    if (tid == 0) {
        float DS = sm.rd.rds[0] + sm.rd.rds[1] + sm.rd.rds[2] + sm.rd.rds[3];
        float OS = sm.rd.ros[0] + sm.rd.ros[1] + sm.rd.ros[2] + sm.rd.ros[3];
        float MM = sm.rd.rmm[0] + sm.rd.rmm[1] + sm.rd.rmm[2] + sm.rd.rmm[3];
        const float bd = (float)BB * (float)DD;
        float2 mine;
        mine.x = wgt * MM / bd;
        mine.y = wgt * DS / bd + wgt * OS / (bd * (float)(DD - 1));
        spart[j] = mine;
        __threadfence();                       // release partial
        int old = atomicAdd(counter, 1);
        sm.rd.is_last = (old == RBLKS - 1);
    }
    __syncthreads();
    if (sm.rd.is_last) {
        __threadfence();                       // acquire all partials
        float2 v = (tid < RBLKS) ? spart[tid] : make_float2(0.f, 0.f);
        float a = v.x, b = v.y;
        #pragma unroll
        for (int off = 32; off > 0; off >>= 1) {
            a += __shfl_down(a, off);
            b += __shfl_down(b, off);
        }
        if (lane == 0) { sm.rd.ra[w] = a; sm.rd.rb[w] = b; }
        __syncthreads();
        if (tid == 0) {
            outscalars[0] = sm.rd.ra[0] + sm.rd.ra[1] + sm.rd.ra[2] + sm.rd.ra[3];
            outscalars[1] = sm.rd.rb[0] + sm.rd.rb[1] + sm.rd.rb[2] + sm.rd.rb[3];
        }
    }
}

// ---------------------------------------------------------------------------
extern "C" void kernel_launch(void* const* d_in, const int* in_sizes, int n_in,
                              void* d_out, int out_size, void* d_ws, size_t ws_size,
                              hipStream_t stream) {
    const float* x = (const float*)d_in[0];
    const float* centers = (const float*)d_in[1];
    float* out = (float*)d_out;
    float* outscalars = out + (size_t)BB * KK;

    char* ws = (char*)d_ws;
    size_t off = 0;
    float*  part     = (float*)(ws + off); off += (size_t)MAXITEMS * DD * DD * 4; // 12.6 MB
    float*  emp_part = (float*)(ws + off); off += (size_t)MAXITEMS * DD * 4;      // 96 KB
    int*    sorted   = (int*)  (ws + off); off += BB * 4;                         // 64 KB
    int*    assign   = (int*)  (ws + off); off += BB * 4;                         // 64 KB
    int*    bhist    = (int*)  (ws + off); off += 256 * KK * 4;                   // 64 KB
    int4*   items    = (int4*) (ws + off); off += 256 * 16;                       // 4 KB
    float*  cw       = (float*)(ws + off); off += 256;
    int*    itemcnt  = (int*)  (ws + off); off += 256;
    int*    ist      = (int*)  (ws + off); off += 256;
    int*    ien      = (int*)  (ws + off); off += 256;
    int*    arrived  = (int*)  (ws + off); off += KK * 4;                         // 256 B
    float2* spart    = (float2*)(ws + off); off += RBLKS * 8;                     // 2 KB
    int*    counter  = (int*)  (ws + off); off += 256;

    k_rows  <<<256, 512, 0, stream>>>(x, centers, out, assign, bhist);
    k_scat  <<<256, 256, 0, stream>>>(assign, bhist, sorted, cw, items,
                                      itemcnt, ist, ien, arrived, counter);
    k_segred<<<MAXITEMS + RBLKS, 256, 0, stream>>>(
        x, sorted, items, itemcnt, ist, ien, cw, centers,
        part, emp_part, arrived, spart, counter, outscalars);
}

// Round 5
// 113.623 us; speedup vs baseline: 2.2925x; 1.3985x over previous
//
#include <hip/hip_runtime.h>

#define BB 16384
#define KK 64
#define DD 128
#define SEG 128          // rows per covariance work-item (single 128-row stage)
#define MAXITEMS 192     // sum_k ceil(cnt_k/SEG) <= 128 + 63 = 191
#define NRB 4            // reduce slabs per cluster
#define RSLAB 4096       // elements per reduce slab
#define RBLKS (KK * NRB) // 256 reducer blocks

typedef __attribute__((ext_vector_type(8))) short bf16x8;
typedef __attribute__((ext_vector_type(4))) float f32x4;

__device__ __forceinline__ unsigned int packbf2(float a, float b) {
    unsigned ua = __float_as_uint(a);
    unsigned ub = __float_as_uint(b);
    ua = (ua + 0x7FFFu + ((ua >> 16) & 1u)) >> 16;   // RNE f32->bf16
    ub = (ub + 0x7FFFu + ((ub >> 16) & 1u)) >> 16;
    return ua | (ub << 16);
}

// ---------------------------------------------------------------------------
// K1: tiled GEMM. Block = 64 rows x 64 clusters, K=128. 256 threads,
// 4 rows x 4 cols per thread (R5: halves DS instructions vs 512-thread 4x2 —
// K1 is DS-pipe-bound; B operand is now one ds_read_b128 of 4 clusters).
// dist = |x|^2 - 2 x.c + |c|^2 ; |x|^2 cancels in softmax AND argmin.
// Emits per-block cluster histogram bhist[b][k]; zeroes the done-counter.
// ---------------------------------------------------------------------------
__global__ __launch_bounds__(256) void k_rows(
    const float* __restrict__ x, const float* __restrict__ centers,
    float* __restrict__ log_resp, int* __restrict__ assign,
    int* __restrict__ bhist, int* __restrict__ counter)
{
    __shared__ float xs[64][132];    // X tile, +4 pad (16B-aligned stride)
    __shared__ float ct[DD][68];     // centers transposed [d][k], 16B-aligned stride
    __shared__ float cn2[KK];
    __shared__ int   lh[KK];

    const int tid = threadIdx.x;
    const int row0 = blockIdx.x * 64;

    if (blockIdx.x == 0 && tid == 0) *counter = 0;
    if (tid < KK) lh[tid] = 0;

    for (int g = tid; g < 64 * 32; g += 256) {
        int r = g >> 5, c4 = g & 31;
        float4 v = ((const float4*)(x + (size_t)(row0 + r) * DD))[c4];
        *(float4*)&xs[r][c4 * 4] = v;
    }
    for (int g = tid; g < KK * 32; g += 256) {
        int k = g >> 5, c4 = g & 31;
        float4 v = ((const float4*)(centers + (size_t)k * DD))[c4];
        ct[c4 * 4 + 0][k] = v.x;
        ct[c4 * 4 + 1][k] = v.y;
        ct[c4 * 4 + 2][k] = v.z;
        ct[c4 * 4 + 3][k] = v.w;
    }
    __syncthreads();
    if (tid < KK) {
        float s = 0.f;
        for (int d = 0; d < DD; ++d) { float c = ct[d][tid]; s = fmaf(c, c, s); }
        cn2[tid] = s;
    }
    __syncthreads();

    const int tr = tid >> 4;         // 0..15: rows tr*4 .. tr*4+3
    const int tc = tid & 15;         // cols tc*4 .. tc*4+3
    const int k0 = tc * 4;

    float acc[4][4];
    #pragma unroll
    for (int i = 0; i < 4; ++i)
        #pragma unroll
        for (int j = 0; j < 4; ++j) acc[i][j] = 0.f;

    for (int d = 0; d < DD; d += 4) {
        float4 b0 = *(const float4*)&ct[d + 0][k0];
        float4 b1 = *(const float4*)&ct[d + 1][k0];
        float4 b2 = *(const float4*)&ct[d + 2][k0];
        float4 b3 = *(const float4*)&ct[d + 3][k0];
        #pragma unroll
        for (int i = 0; i < 4; ++i) {
            float4 a = *(const float4*)&xs[tr * 4 + i][d];
            acc[i][0] = fmaf(a.x, b0.x, acc[i][0]);
            acc[i][0] = fmaf(a.y, b1.x, acc[i][0]);
            acc[i][0] = fmaf(a.z, b2.x, acc[i][0]);
            acc[i][0] = fmaf(a.w, b3.x, acc[i][0]);
            acc[i][1] = fmaf(a.x, b0.y, acc[i][1]);
            acc[i][1] = fmaf(a.y, b1.y, acc[i][1]);
            acc[i][1] = fmaf(a.z, b2.y, acc[i][1]);
            acc[i][1] = fmaf(a.w, b3.y, acc[i][1]);
            acc[i][2] = fmaf(a.x, b0.z, acc[i][2]);
            acc[i][2] = fmaf(a.y, b1.z, acc[i][2]);
            acc[i][2] = fmaf(a.z, b2.z, acc[i][2]);
            acc[i][2] = fmaf(a.w, b3.z, acc[i][2]);
            acc[i][3] = fmaf(a.x, b0.w, acc[i][3]);
            acc[i][3] = fmaf(a.y, b1.w, acc[i][3]);
            acc[i][3] = fmaf(a.z, b2.w, acc[i][3]);
            acc[i][3] = fmaf(a.w, b3.w, acc[i][3]);
        }
    }

    const float cn0 = 0.5f * cn2[k0 + 0];
    const float cn1 = 0.5f * cn2[k0 + 1];
    const float cn2v = 0.5f * cn2[k0 + 2];
    const float cn3 = 0.5f * cn2[k0 + 3];
    #pragma unroll
    for (int i = 0; i < 4; ++i) {
        const int row = row0 + tr * 4 + i;
        float v0 = acc[i][0] - cn0;
        float v1 = acc[i][1] - cn1;
        float v2 = acc[i][2] - cn2v;
        float v3 = acc[i][3] - cn3;
        // local argmax, lowest index on ties (matches jnp.argmin semantics)
        float m = v0; int idx = k0;
        if (v1 > m) { m = v1; idx = k0 + 1; }
        if (v2 > m) { m = v2; idx = k0 + 2; }
        if (v3 > m) { m = v3; idx = k0 + 3; }
        #pragma unroll
        for (int off = 1; off < 16; off <<= 1) {   // 16-lane row group
            float ov = __shfl_xor(m, off);
            int   oi = __shfl_xor(idx, off);
            if (ov > m || (ov == m && oi < idx)) { m = ov; idx = oi; }
        }
        float s = expf(v0 - m) + expf(v1 - m) + expf(v2 - m) + expf(v3 - m);
        #pragma unroll
        for (int off = 1; off < 16; off <<= 1) s += __shfl_xor(s, off);
        float ls = logf(s);
        float4 lr;
        lr.x = fmaxf(v0 - m - ls, -18.4206807f);  // log(1e-8)
        lr.y = fmaxf(v1 - m - ls, -18.4206807f);
        lr.z = fmaxf(v2 - m - ls, -18.4206807f);
        lr.w = fmaxf(v3 - m - ls, -18.4206807f);
        *(float4*)&log_resp[(size_t)row * KK + k0] = lr;
        if (tc == 0) {
            assign[row] = idx;
            atomicAdd(&lh[idx], 1);
        }
    }
    __syncthreads();
    if (tid < KK) bhist[blockIdx.x * KK + tid] = lh[tid];   // coalesced 256B
}

// ---------------------------------------------------------------------------
// K2 (256 blocks): parallel counting-sort scatter (R1-verified). Block 0
// emits items (SEG=128) / ist / ien / itemcnt / cw; item emission parallel
// across 64 threads.
// ---------------------------------------------------------------------------
__global__ __launch_bounds__(256) void k_scat(
    const int* __restrict__ assign, const int* __restrict__ bhist,
    int* __restrict__ sorted, float* __restrict__ cw,
    int4* __restrict__ items, int* __restrict__ item_count,
    int* __restrict__ ist, int* __restrict__ ien)
{
    __shared__ int ph_tot[4][KK], ph_pre[4][KK];
    __shared__ int cnt_s[KK], pre_s[KK], base_s[KK], cur_s[KK];
    __shared__ int iof[KK + 1];

    const int tid = threadIdx.x;
    const int b = blockIdx.x;
    const int t = tid & 63, q = tid >> 6;

    int tot = 0, pre = 0;
    const int bb0 = q * 64;
    for (int bb = bb0; bb < bb0 + 64; ++bb) {
        int v = bhist[bb * KK + t];          // lanes consecutive: coalesced
        tot += v;
        if (bb < b) pre += v;
    }
    ph_tot[q][t] = tot; ph_pre[q][t] = pre;
    __syncthreads();

    if (tid < KK) {
        cnt_s[tid] = ph_tot[0][tid] + ph_tot[1][tid] + ph_tot[2][tid] + ph_tot[3][tid];
        pre_s[tid] = ph_pre[0][tid] + ph_pre[1][tid] + ph_pre[2][tid] + ph_pre[3][tid];
        cur_s[tid] = 0;
    }
    __syncthreads();
    if (tid == 0) {
        int base = 0;
        for (int k = 0; k < KK; ++k) { base_s[k] = base; base += cnt_s[k]; }
    }
    __syncthreads();

    if (tid < 64) {
        int r = b * 64 + tid;
        int a = assign[r];
        int p = base_s[a] + pre_s[a] + atomicAdd(&cur_s[a], 1);
        sorted[p] = r;                       // intra-cluster order: don't care
    }

    if (b == 0) {
        if (tid < KK) cw[tid] = (float)cnt_s[tid];
        if (tid == 0) {
            int ic = 0;
            for (int k = 0; k < KK; ++k) {
                iof[k] = ic;
                ic += (cnt_s[k] + SEG - 1) / SEG;
            }
            iof[KK] = ic;
            *item_count = ic;
        }
        __syncthreads();                     // block-uniform branch: legal
        if (tid < KK) {
            const int k = tid, c = cnt_s[k], io = iof[k];
            ist[k] = io;
            ien[k] = iof[k + 1];
            int j = 0;
            for (int s = 0; s < c; s += SEG, ++j) {
                int4 it; it.x = k; it.y = base_s[k] + s;
                it.z = min(SEG, c - s); it.w = 0;
                items[io + j] = it;
            }
        }
    }
}

// ---------------------------------------------------------------------------
// K3 (MFMA): one block per item (<=128 rows). Sxx = X^T X via
// mfma_f32_16x16x32_bf16. Column sums go NON-atomically to emp_part[item][d];
// k_redfinal sums emp_part.
// ---------------------------------------------------------------------------
__global__ __launch_bounds__(256) void k_seg(
    const float* __restrict__ x, const int* __restrict__ sorted,
    const int4* __restrict__ items, const int* __restrict__ item_count,
    float* __restrict__ part, float* __restrict__ emp_part)
{
    if ((int)blockIdx.x >= *item_count) return;
    int4 it = items[blockIdx.x];
    const int gstart = it.y, len = it.z;   // len <= 128

    __shared__ int rows_s[128];
    __shared__ unsigned int XT[DD][68];   // XT[d][j] = bf16 pair rows (2j,2j+1)

    const int tid = threadIdx.x;
    const int w = tid >> 6, lane = tid & 63;
    const int c4 = lane & 15, q = lane >> 4;

    f32x4 acc[2][8];
    #pragma unroll
    for (int h = 0; h < 2; ++h)
        #pragma unroll
        for (int nt = 0; nt < 8; ++nt)
            acc[h][nt] = (f32x4){0.f, 0.f, 0.f, 0.f};
    float colsum = 0.f;

    for (int half = 0; half < 2; ++half) {
        const int hoff = half * 128;
        const int hlen = min(128, len - hoff);     // uniform across block
        if (hlen <= 0) break;

        __syncthreads();   // WAR: prev half's XT/rows_s reads complete
        if (tid < hlen) rows_s[tid] = sorted[gstart + hoff + tid];
        __syncthreads();

        // stage: wave w owns dims [w*32, w*32+32); lane owns row pair
        {
            const int r0 = 2 * lane, r1 = 2 * lane + 1;
            const int d0 = w * 32;
            const float* p0 = x + (size_t)rows_s[r0 < hlen ? r0 : 0] * DD + d0;
            const float* p1 = x + (size_t)rows_s[r1 < hlen ? r1 : 0] * DD + d0;
            #pragma unroll
            for (int i = 0; i < 8; ++i) {
                float4 a = make_float4(0.f, 0.f, 0.f, 0.f);
                float4 b = make_float4(0.f, 0.f, 0.f, 0.f);
                if (r0 < hlen) a = *(const float4*)(p0 + 4 * i);
                if (r1 < hlen) b = *(const float4*)(p1 + 4 * i);
                XT[d0 + 4 * i + 0][lane] = packbf2(a.x, b.x);
                XT[d0 + 4 * i + 1][lane] = packbf2(a.y, b.y);
                XT[d0 + 4 * i + 2][lane] = packbf2(a.z, b.z);
                XT[d0 + 4 * i + 3][lane] = packbf2(a.w, b.w);
            }
        }
        __syncthreads();

        // column sums (f32 from the bf16 data): thread d < 128
        if (tid < DD) {
            float s = 0.f;
            #pragma unroll
            for (int j4 = 0; j4 < 16; ++j4) {
                uint4 v = *(const uint4*)&XT[tid][j4 * 4];
                s += __uint_as_float(v.x << 16) + __uint_as_float(v.x & 0xFFFF0000u);
                s += __uint_as_float(v.y << 16) + __uint_as_float(v.y & 0xFFFF0000u);
                s += __uint_as_float(v.z << 16) + __uint_as_float(v.z & 0xFFFF0000u);
                s += __uint_as_float(v.w << 16) + __uint_as_float(v.w & 0xFFFF0000u);
            }
            colsum += s;
        }

        // MFMA: wave w owns m-tiles {2w, 2w+1} x n-tiles 0..7
        #pragma unroll
        for (int c = 0; c < 4; ++c) {          // K chunks of 32 rows
            const int ku = c * 16 + q * 4;     // u32 index: k0 = c*32 + q*8
            bf16x8 a0 = *(const bf16x8*)&XT[(2 * w + 0) * 16 + c4][ku];
            bf16x8 a1 = *(const bf16x8*)&XT[(2 * w + 1) * 16 + c4][ku];
            #pragma unroll
            for (int nt = 0; nt < 8; ++nt) {
                bf16x8 b = *(const bf16x8*)&XT[nt * 16 + c4][ku];
                acc[0][nt] = __builtin_amdgcn_mfma_f32_16x16x32_bf16(a0, b, acc[0][nt], 0, 0, 0);
                acc[1][nt] = __builtin_amdgcn_mfma_f32_16x16x32_bf16(a1, b, acc[1][nt], 0, 0, 0);
            }
        }
    }

    if (tid < DD) emp_part[blockIdx.x * DD + tid] = colsum;   // non-atomic

    // C/D layout: col = lane&15, row = quad*4 + reg  [m89/m91 verified]
    float* pb = part + (size_t)blockIdx.x * (DD * DD);
    #pragma unroll
    for (int h = 0; h < 2; ++h) {
        const int m0 = (2 * w + h) * 16 + q * 4;
        #pragma unroll
        for (int nt = 0; nt < 8; ++nt) {
            const int n = nt * 16 + c4;
            pb[(m0 + 0) * DD + n] = acc[h][nt].x;
            pb[(m0 + 1) * DD + n] = acc[h][nt].y;
            pb[(m0 + 2) * DD + n] = acc[h][nt].z;
            pb[(m0 + 3) * DD + n] = acc[h][nt].w;
        }
    }
}

// ---------------------------------------------------------------------------
// K4: grid = KK x NRB(=4) slabs of 4096 elems. Wave-streaming reduce of item
// partials, emp summed from emp_part, centered covariance, then NON-atomic
// spart[block] + counter; last block sums 256 partials and writes the two
// output scalars.
// ---------------------------------------------------------------------------
__global__ __launch_bounds__(256) void k_redfinal(
    const float* __restrict__ part, const float* __restrict__ emp_part,
    const float* __restrict__ cw, const float* __restrict__ centers,
    const int* __restrict__ ist, const int* __restrict__ ien,
    float2* __restrict__ spart, int* __restrict__ counter,
    float* __restrict__ outscalars)
{
    const int k = blockIdx.x >> 2;
    const int p = blockIdx.x & 3;
    const int i0 = ist[k], i1 = ien[k];
    const int tid = threadIdx.x;
    const int w = tid >> 6, lane = tid & 63;
    const float wgt = cw[k];
    const float inv = 1.0f / (wgt + 1e-7f);

    __shared__ float mu_s[DD], emp_s[DD];
    __shared__ float emp2[2][DD];
    __shared__ float red[4][RSLAB];      // 64 KB

    // emp = sum over items of emp_part (2 thread-groups x 2 chains = MLP 4)
    {
        const int dh = tid & 127, hf = tid >> 7;
        float e0 = 0.f, e1 = 0.f;
        int it = i0 + hf;
        for (; it + 2 < i1; it += 4) {
            e0 += emp_part[it * DD + dh];
            e1 += emp_part[(it + 2) * DD + dh];
        }
        if (it < i1) e0 += emp_part[it * DD + dh];
        emp2[hf][dh] = e0 + e1;
    }
    __syncthreads();
    if (tid < DD) {
        float e = emp2[0][tid] + emp2[1][tid];
        emp_s[tid] = e;
        mu_s[tid] = e * inv;
    }

    float4 acc[16];
    #pragma unroll
    for (int c = 0; c < 16; ++c) acc[c] = make_float4(0.f, 0.f, 0.f, 0.f);

    const int base = p * RSLAB;
    for (int it = i0 + w; it < i1; it += 4) {
        const float* pb = part + (size_t)it * (DD * DD) + base;
        #pragma unroll
        for (int c = 0; c < 16; ++c) {
            float4 v = *(const float4*)&pb[c * 256 + lane * 4];
            acc[c].x += v.x; acc[c].y += v.y; acc[c].z += v.z; acc[c].w += v.w;
        }
    }
    #pragma unroll
    for (int c = 0; c < 16; ++c)
        *(float4*)&red[w][c * 256 + lane * 4] = acc[c];
    __syncthreads();   // also orders mu_s/emp_s writes

    float ds = 0.f, os = 0.f, mm = 0.f;
    #pragma unroll
    for (int jj = 0; jj < 16; ++jj) {
        int el = jj * 256 + tid;               // stride-1 across lanes
        float sx = red[0][el] + red[1][el] + red[2][el] + red[3][el];
        int gel = base + el;
        int d = gel >> 7, e = gel & 127;
        float ctv = sx - mu_s[d] * emp_s[e] - emp_s[d] * mu_s[e]
                  + wgt * mu_s[d] * mu_s[e];
        float v = ctv * inv;
        if (d == e) { float t = v - 1.f; ds += t * t; }
        else        { os += v * v; }
    }
    if (p == 0 && tid < DD) {
        float t = mu_s[tid] - centers[k * DD + tid];
        mm = t * t;
    }

    #pragma unroll
    for (int off = 32; off > 0; off >>= 1) {
        ds += __shfl_down(ds, off);
        os += __shfl_down(os, off);
        mm += __shfl_down(mm, off);
    }
    __shared__ float rds[4], ros[4], rmm[4];
    __shared__ int is_last;
    if (lane == 0) { rds[w] = ds; ros[w] = os; rmm[w] = mm; }
    __syncthreads();
    if (tid == 0) {
        float DS = rds[0] + rds[1] + rds[2] + rds[3];
        float OS = ros[0] + ros[1] + ros[2] + ros[3];
        float MM = rmm[0] + rmm[1] + rmm[2] + rmm[3];
        const float bd = (float)BB * (float)DD;
        float2 mine;
        mine.x = wgt * MM / bd;
        mine.y = wgt * DS / bd + wgt * OS / (bd * (float)(DD - 1));
        spart[blockIdx.x] = mine;
        __threadfence();                       // release partial
        int old = atomicAdd(counter, 1);
        is_last = (old == RBLKS - 1);
    }
    __syncthreads();
    if (is_last) {
        __threadfence();                       // acquire all partials
        float2 v = (tid < RBLKS) ? spart[tid] : make_float2(0.f, 0.f);
        float a = v.x, b = v.y;
        #pragma unroll
        for (int off = 32; off > 0; off >>= 1) {
            a += __shfl_down(a, off);
            b += __shfl_down(b, off);
        }
        __shared__ float ra[4], rb[4];
        if (lane == 0) { ra[w] = a; rb[w] = b; }
        __syncthreads();
        if (tid == 0) {
            outscalars[0] = ra[0] + ra[1] + ra[2] + ra[3];
            outscalars[1] = rb[0] + rb[1] + rb[2] + rb[3];
        }
    }
}

// ---------------------------------------------------------------------------
extern "C" void kernel_launch(void* const* d_in, const int* in_sizes, int n_in,
                              void* d_out, int out_size, void* d_ws, size_t ws_size,
                              hipStream_t stream) {
    const float* x = (const float*)d_in[0];
    const float* centers = (const float*)d_in[1];
    float* out = (float*)d_out;
    float* outscalars = out + (size_t)BB * KK;

    char* ws = (char*)d_ws;
    size_t off = 0;
    float*  part     = (float*)(ws + off); off += (size_t)MAXITEMS * DD * DD * 4; // 12.6 MB
    float*  emp_part = (float*)(ws + off); off += (size_t)MAXITEMS * DD * 4;      // 96 KB
    int*    sorted   = (int*)  (ws + off); off += BB * 4;                         // 64 KB
    int*    assign   = (int*)  (ws + off); off += BB * 4;                         // 64 KB
    int*    bhist    = (int*)  (ws + off); off += 256 * KK * 4;                   // 64 KB
    int4*   items    = (int4*) (ws + off); off += 256 * 16;                       // 4 KB
    float*  cw       = (float*)(ws + off); off += 256;
    int*    itemcnt  = (int*)  (ws + off); off += 256;
    int*    ist      = (int*)  (ws + off); off += 256;
    int*    ien      = (int*)  (ws + off); off += 256;
    float2* spart    = (float2*)(ws + off); off += RBLKS * 8;                     // 2 KB
    int*    counter  = (int*)  (ws + off); off += 256;

    k_rows    <<<256, 256, 0, stream>>>(x, centers, out, assign, bhist, counter);
    k_scat    <<<256, 256, 0, stream>>>(assign, bhist, sorted, cw, items,
                                        itemcnt, ist, ien);
    k_seg     <<<MAXITEMS, 256, 0, stream>>>(x, sorted, items, itemcnt,
                                             part, emp_part);
    k_redfinal<<<RBLKS, 256, 0, stream>>>(part, emp_part, cw, centers, ist, ien,
                                          spart, counter, outscalars);
}

// Round 6
// 112.200 us; speedup vs baseline: 2.3215x; 1.0127x over previous
//
#include <hip/hip_runtime.h>

#define BB 16384
#define KK 64
#define DD 128
#define SEG 128          // rows per covariance work-item (single 128-row stage)
#define MAXITEMS 192     // sum_k ceil(cnt_k/SEG) <= 128 + 63 = 191
#define NRB 4            // reduce slabs per cluster
#define RSLAB 4096       // elements per reduce slab
#define RBLKS (KK * NRB) // 256 reducer blocks

typedef __attribute__((ext_vector_type(8))) short bf16x8;
typedef __attribute__((ext_vector_type(4))) float f32x4;

__device__ __forceinline__ unsigned int packbf2(float a, float b) {
    unsigned ua = __float_as_uint(a);
    unsigned ub = __float_as_uint(b);
    ua = (ua + 0x7FFFu + ((ua >> 16) & 1u)) >> 16;   // RNE f32->bf16
    ub = (ub + 0x7FFFu + ((ub >> 16) & 1u)) >> 16;
    return ua | (ub << 16);
}

__device__ __forceinline__ unsigned bf16rne(float f) {
    unsigned u = __float_as_uint(f);
    return (u + 0x7FFFu + ((u >> 16) & 1u)) >> 16;
}
__device__ __forceinline__ float bf16tof(unsigned h) {
    return __uint_as_float(h << 16);
}
// split float4 into bf16-hi pair-words and bf16-lo (residual) pair-words
__device__ __forceinline__ void split4(float4 v, uint2& hi, uint2& lo) {
    unsigned hx = bf16rne(v.x), hy = bf16rne(v.y);
    unsigned hz = bf16rne(v.z), hw = bf16rne(v.w);
    hi.x = hx | (hy << 16); hi.y = hz | (hw << 16);
    unsigned lx = bf16rne(v.x - bf16tof(hx)), ly = bf16rne(v.y - bf16tof(hy));
    unsigned lz = bf16rne(v.z - bf16tof(hz)), lw = bf16rne(v.w - bf16tof(hw));
    lo.x = lx | (ly << 16); lo.y = lz | (lw << 16);
}

// ---------------------------------------------------------------------------
// K1 (R6): distance GEMM on the MATRIX pipe via split-bf16 3-pass MFMA.
// R5 post-mortem: the f32 VALU FMA work (>=3.4us at 100% util) was the floor;
// no f32 tiling removes it. x.c = xh.ch + xh.cl + xl.ch in f32 accumulators
// (~1e-5 relative error -> log_resp/argmin unaffected at tolerance).
// Fragment addressing copied from harness-verified K3 pattern.
// dist = |x|^2 - 2 x.c + |c|^2 ; |x|^2 cancels in softmax AND argmin;
// |c|^2 computed in exact f32 from global.
// ---------------------------------------------------------------------------
__global__ __launch_bounds__(256) void k_rows(
    const float* __restrict__ x, const float* __restrict__ centers,
    float* __restrict__ log_resp, int* __restrict__ assign,
    int* __restrict__ bhist, int* __restrict__ counter)
{
    __shared__ unsigned int XH[64][68], XLo[64][68];   // x rows, bf16 hi/lo
    __shared__ unsigned int CH[64][68], CLo[64][68];   // center rows, bf16 hi/lo
    __shared__ float cn2_s[KK];
    __shared__ int   lh[KK];

    const int tid = threadIdx.x;
    const int row0 = blockIdx.x * 64;

    if (blockIdx.x == 0 && tid == 0) *counter = 0;
    if (tid < KK) lh[tid] = 0;

    for (int g = tid; g < 64 * 32; g += 256) {
        int r = g >> 5, c4g = g & 31;
        float4 v = ((const float4*)(x + (size_t)(row0 + r) * DD))[c4g];
        uint2 hi, lo; split4(v, hi, lo);
        *(uint2*)&XH[r][c4g * 2] = hi;
        *(uint2*)&XLo[r][c4g * 2] = lo;
    }
    for (int g = tid; g < 64 * 32; g += 256) {
        int k = g >> 5, c4g = g & 31;
        float4 v = ((const float4*)(centers + (size_t)k * DD))[c4g];
        uint2 hi, lo; split4(v, hi, lo);
        *(uint2*)&CH[k][c4g * 2] = hi;
        *(uint2*)&CLo[k][c4g * 2] = lo;
    }
    if (tid < KK) {       // |c|^2 in exact f32 (L2-hot re-read, 32KB)
        float s = 0.f;
        const float4* cp = (const float4*)(centers + (size_t)tid * DD);
        for (int c4g = 0; c4g < 32; ++c4g) {
            float4 v = cp[c4g];
            s = fmaf(v.x, v.x, s); s = fmaf(v.y, v.y, s);
            s = fmaf(v.z, v.z, s); s = fmaf(v.w, v.w, s);
        }
        cn2_s[tid] = s;
    }
    __syncthreads();

    const int w = tid >> 6, lane = tid & 63;   // wave w owns m-tile w (16 rows)
    const int c4 = lane & 15, q = lane >> 4;

    f32x4 acc[4];
    #pragma unroll
    for (int nt = 0; nt < 4; ++nt) acc[nt] = (f32x4){0.f, 0.f, 0.f, 0.f};

    #pragma unroll
    for (int c = 0; c < 4; ++c) {              // K chunks of 32 dims
        const int ku = c * 16 + q * 4;         // u32 index: d0 = c*32 + q*8
        bf16x8 ah = *(const bf16x8*)&XH[w * 16 + c4][ku];
        bf16x8 al = *(const bf16x8*)&XLo[w * 16 + c4][ku];
        #pragma unroll
        for (int nt = 0; nt < 4; ++nt) {
            bf16x8 bh = *(const bf16x8*)&CH[nt * 16 + c4][ku];
            bf16x8 bl = *(const bf16x8*)&CLo[nt * 16 + c4][ku];
            acc[nt] = __builtin_amdgcn_mfma_f32_16x16x32_bf16(ah, bh, acc[nt], 0, 0, 0);
            acc[nt] = __builtin_amdgcn_mfma_f32_16x16x32_bf16(ah, bl, acc[nt], 0, 0, 0);
            acc[nt] = __builtin_amdgcn_mfma_f32_16x16x32_bf16(al, bh, acc[nt], 0, 0, 0);
        }
    }

    // C/D layout: col = nt*16 + (lane&15), row = w*16 + q*4 + reg [K3-verified]
    float cn[4];
    #pragma unroll
    for (int nt = 0; nt < 4; ++nt) cn[nt] = 0.5f * cn2_s[nt * 16 + c4];

    #pragma unroll
    for (int j = 0; j < 4; ++j) {
        const int row = row0 + w * 16 + q * 4 + j;
        float v0 = acc[0][j] - cn[0];
        float v1 = acc[1][j] - cn[1];
        float v2 = acc[2][j] - cn[2];
        float v3 = acc[3][j] - cn[3];
        // local argmax, ascending col order + strict > : lowest index on ties
        float m = v0; int idx = c4;
        if (v1 > m) { m = v1; idx = 16 + c4; }
        if (v2 > m) { m = v2; idx = 32 + c4; }
        if (v3 > m) { m = v3; idx = 48 + c4; }
        #pragma unroll
        for (int off = 1; off < 16; off <<= 1) {   // 16-lane row group
            float ov = __shfl_xor(m, off);
            int   oi = __shfl_xor(idx, off);
            if (ov > m || (ov == m && oi < idx)) { m = ov; idx = oi; }
        }
        float s = expf(v0 - m) + expf(v1 - m) + expf(v2 - m) + expf(v3 - m);
        #pragma unroll
        for (int off = 1; off < 16; off <<= 1) s += __shfl_xor(s, off);
        float ls = logf(s);
        log_resp[(size_t)row * KK +  0 + c4] = fmaxf(v0 - m - ls, -18.4206807f);
        log_resp[(size_t)row * KK + 16 + c4] = fmaxf(v1 - m - ls, -18.4206807f);
        log_resp[(size_t)row * KK + 32 + c4] = fmaxf(v2 - m - ls, -18.4206807f);
        log_resp[(size_t)row * KK + 48 + c4] = fmaxf(v3 - m - ls, -18.4206807f);
        if (c4 == 0) {
            assign[row] = idx;
            atomicAdd(&lh[idx], 1);
        }
    }
    __syncthreads();
    if (tid < KK) bhist[blockIdx.x * KK + tid] = lh[tid];   // coalesced 256B
}

// ---------------------------------------------------------------------------
// K2 (256 blocks): parallel counting-sort scatter (R1-verified). Block 0
// emits items (SEG=128) / ist / ien / itemcnt / cw; item emission parallel
// across 64 threads.
// ---------------------------------------------------------------------------
__global__ __launch_bounds__(256) void k_scat(
    const int* __restrict__ assign, const int* __restrict__ bhist,
    int* __restrict__ sorted, float* __restrict__ cw,
    int4* __restrict__ items, int* __restrict__ item_count,
    int* __restrict__ ist, int* __restrict__ ien)
{
    __shared__ int ph_tot[4][KK], ph_pre[4][KK];
    __shared__ int cnt_s[KK], pre_s[KK], base_s[KK], cur_s[KK];
    __shared__ int iof[KK + 1];

    const int tid = threadIdx.x;
    const int b = blockIdx.x;
    const int t = tid & 63, q = tid >> 6;

    int tot = 0, pre = 0;
    const int bb0 = q * 64;
    for (int bb = bb0; bb < bb0 + 64; ++bb) {
        int v = bhist[bb * KK + t];          // lanes consecutive: coalesced
        tot += v;
        if (bb < b) pre += v;
    }
    ph_tot[q][t] = tot; ph_pre[q][t] = pre;
    __syncthreads();

    if (tid < KK) {
        cnt_s[tid] = ph_tot[0][tid] + ph_tot[1][tid] + ph_tot[2][tid] + ph_tot[3][tid];
        pre_s[tid] = ph_pre[0][tid] + ph_pre[1][tid] + ph_pre[2][tid] + ph_pre[3][tid];
        cur_s[tid] = 0;
    }
    __syncthreads();
    if (tid == 0) {
        int base = 0;
        for (int k = 0; k < KK; ++k) { base_s[k] = base; base += cnt_s[k]; }
    }
    __syncthreads();

    if (tid < 64) {
        int r = b * 64 + tid;
        int a = assign[r];
        int p = base_s[a] + pre_s[a] + atomicAdd(&cur_s[a], 1);
        sorted[p] = r;                       // intra-cluster order: don't care
    }

    if (b == 0) {
        if (tid < KK) cw[tid] = (float)cnt_s[tid];
        if (tid == 0) {
            int ic = 0;
            for (int k = 0; k < KK; ++k) {
                iof[k] = ic;
                ic += (cnt_s[k] + SEG - 1) / SEG;
            }
            iof[KK] = ic;
            *item_count = ic;
        }
        __syncthreads();                     // block-uniform branch: legal
        if (tid < KK) {
            const int k = tid, c = cnt_s[k], io = iof[k];
            ist[k] = io;
            ien[k] = iof[k + 1];
            int j = 0;
            for (int s = 0; s < c; s += SEG, ++j) {
                int4 it; it.x = k; it.y = base_s[k] + s;
                it.z = min(SEG, c - s); it.w = 0;
                items[io + j] = it;
            }
        }
    }
}

// ---------------------------------------------------------------------------
// K3 (MFMA): one block per item (<=128 rows). Sxx = X^T X via
// mfma_f32_16x16x32_bf16. Column sums go NON-atomically to emp_part[item][d];
// k_redfinal sums emp_part.
// ---------------------------------------------------------------------------
__global__ __launch_bounds__(256) void k_seg(
    const float* __restrict__ x, const int* __restrict__ sorted,
    const int4* __restrict__ items, const int* __restrict__ item_count,
    float* __restrict__ part, float* __restrict__ emp_part)
{
    if ((int)blockIdx.x >= *item_count) return;
    int4 it = items[blockIdx.x];
    const int gstart = it.y, len = it.z;   // len <= 128

    __shared__ int rows_s[128];
    __shared__ unsigned int XT[DD][68];   // XT[d][j] = bf16 pair rows (2j,2j+1)

    const int tid = threadIdx.x;
    const int w = tid >> 6, lane = tid & 63;
    const int c4 = lane & 15, q = lane >> 4;

    f32x4 acc[2][8];
    #pragma unroll
    for (int h = 0; h < 2; ++h)
        #pragma unroll
        for (int nt = 0; nt < 8; ++nt)
            acc[h][nt] = (f32x4){0.f, 0.f, 0.f, 0.f};
    float colsum = 0.f;

    for (int half = 0; half < 2; ++half) {
        const int hoff = half * 128;
        const int hlen = min(128, len - hoff);     // uniform across block
        if (hlen <= 0) break;

        __syncthreads();   // WAR: prev half's XT/rows_s reads complete
        if (tid < hlen) rows_s[tid] = sorted[gstart + hoff + tid];
        __syncthreads();

        // stage: wave w owns dims [w*32, w*32+32); lane owns row pair
        {
            const int r0 = 2 * lane, r1 = 2 * lane + 1;
            const int d0 = w * 32;
            const float* p0 = x + (size_t)rows_s[r0 < hlen ? r0 : 0] * DD + d0;
            const float* p1 = x + (size_t)rows_s[r1 < hlen ? r1 : 0] * DD + d0;
            #pragma unroll
            for (int i = 0; i < 8; ++i) {
                float4 a = make_float4(0.f, 0.f, 0.f, 0.f);
                float4 b = make_float4(0.f, 0.f, 0.f, 0.f);
                if (r0 < hlen) a = *(const float4*)(p0 + 4 * i);
                if (r1 < hlen) b = *(const float4*)(p1 + 4 * i);
                XT[d0 + 4 * i + 0][lane] = packbf2(a.x, b.x);
                XT[d0 + 4 * i + 1][lane] = packbf2(a.y, b.y);
                XT[d0 + 4 * i + 2][lane] = packbf2(a.z, b.z);
                XT[d0 + 4 * i + 3][lane] = packbf2(a.w, b.w);
            }
        }
        __syncthreads();

        // column sums (f32 from the bf16 data): thread d < 128
        if (tid < DD) {
            float s = 0.f;
            #pragma unroll
            for (int j4 = 0; j4 < 16; ++j4) {
                uint4 v = *(const uint4*)&XT[tid][j4 * 4];
                s += __uint_as_float(v.x << 16) + __uint_as_float(v.x & 0xFFFF0000u);
                s += __uint_as_float(v.y << 16) + __uint_as_float(v.y & 0xFFFF0000u);
                s += __uint_as_float(v.z << 16) + __uint_as_float(v.z & 0xFFFF0000u);
                s += __uint_as_float(v.w << 16) + __uint_as_float(v.w & 0xFFFF0000u);
            }
            colsum += s;
        }

        // MFMA: wave w owns m-tiles {2w, 2w+1} x n-tiles 0..7
        #pragma unroll
        for (int c = 0; c < 4; ++c) {          // K chunks of 32 rows
            const int ku = c * 16 + q * 4;     // u32 index: k0 = c*32 + q*8
            bf16x8 a0 = *(const bf16x8*)&XT[(2 * w + 0) * 16 + c4][ku];
            bf16x8 a1 = *(const bf16x8*)&XT[(2 * w + 1) * 16 + c4][ku];
            #pragma unroll
            for (int nt = 0; nt < 8; ++nt) {
                bf16x8 b = *(const bf16x8*)&XT[nt * 16 + c4][ku];
                acc[0][nt] = __builtin_amdgcn_mfma_f32_16x16x32_bf16(a0, b, acc[0][nt], 0, 0, 0);
                acc[1][nt] = __builtin_amdgcn_mfma_f32_16x16x32_bf16(a1, b, acc[1][nt], 0, 0, 0);
            }
        }
    }

    if (tid < DD) emp_part[blockIdx.x * DD + tid] = colsum;   // non-atomic

    // C/D layout: col = lane&15, row = quad*4 + reg  [m89/m91 verified]
    float* pb = part + (size_t)blockIdx.x * (DD * DD);
    #pragma unroll
    for (int h = 0; h < 2; ++h) {
        const int m0 = (2 * w + h) * 16 + q * 4;
        #pragma unroll
        for (int nt = 0; nt < 8; ++nt) {
            const int n = nt * 16 + c4;
            pb[(m0 + 0) * DD + n] = acc[h][nt].x;
            pb[(m0 + 1) * DD + n] = acc[h][nt].y;
            pb[(m0 + 2) * DD + n] = acc[h][nt].z;
            pb[(m0 + 3) * DD + n] = acc[h][nt].w;
        }
    }
}

// ---------------------------------------------------------------------------
// K4: grid = KK x NRB(=4) slabs of 4096 elems. Wave-streaming reduce of item
// partials, emp summed from emp_part, centered covariance, then NON-atomic
// spart[block] + counter; last block sums 256 partials and writes the two
// output scalars.
// ---------------------------------------------------------------------------
__global__ __launch_bounds__(256) void k_redfinal(
    const float* __restrict__ part, const float* __restrict__ emp_part,
    const float* __restrict__ cw, const float* __restrict__ centers,
    const int* __restrict__ ist, const int* __restrict__ ien,
    float2* __restrict__ spart, int* __restrict__ counter,
    float* __restrict__ outscalars)
{
    const int k = blockIdx.x >> 2;
    const int p = blockIdx.x & 3;
    const int i0 = ist[k], i1 = ien[k];
    const int tid = threadIdx.x;
    const int w = tid >> 6, lane = tid & 63;
    const float wgt = cw[k];
    const float inv = 1.0f / (wgt + 1e-7f);

    __shared__ float mu_s[DD], emp_s[DD];
    __shared__ float emp2[2][DD];
    __shared__ float red[4][RSLAB];      // 64 KB

    // emp = sum over items of emp_part (2 thread-groups x 2 chains = MLP 4)
    {
        const int dh = tid & 127, hf = tid >> 7;
        float e0 = 0.f, e1 = 0.f;
        int it = i0 + hf;
        for (; it + 2 < i1; it += 4) {
            e0 += emp_part[it * DD + dh];
            e1 += emp_part[(it + 2) * DD + dh];
        }
        if (it < i1) e0 += emp_part[it * DD + dh];
        emp2[hf][dh] = e0 + e1;
    }
    __syncthreads();
    if (tid < DD) {
        float e = emp2[0][tid] + emp2[1][tid];
        emp_s[tid] = e;
        mu_s[tid] = e * inv;
    }

    float4 acc[16];
    #pragma unroll
    for (int c = 0; c < 16; ++c) acc[c] = make_float4(0.f, 0.f, 0.f, 0.f);

    const int base = p * RSLAB;
    for (int it = i0 + w; it < i1; it += 4) {
        const float* pb = part + (size_t)it * (DD * DD) + base;
        #pragma unroll
        for (int c = 0; c < 16; ++c) {
            float4 v = *(const float4*)&pb[c * 256 + lane * 4];
            acc[c].x += v.x; acc[c].y += v.y; acc[c].z += v.z; acc[c].w += v.w;
        }
    }
    #pragma unroll
    for (int c = 0; c < 16; ++c)
        *(float4*)&red[w][c * 256 + lane * 4] = acc[c];
    __syncthreads();   // also orders mu_s/emp_s writes

    float ds = 0.f, os = 0.f, mm = 0.f;
    #pragma unroll
    for (int jj = 0; jj < 16; ++jj) {
        int el = jj * 256 + tid;               // stride-1 across lanes
        float sx = red[0][el] + red[1][el] + red[2][el] + red[3][el];
        int gel = base + el;
        int d = gel >> 7, e = gel & 127;
        float ctv = sx - mu_s[d] * emp_s[e] - emp_s[d] * mu_s[e]
                  + wgt * mu_s[d] * mu_s[e];
        float v = ctv * inv;
        if (d == e) { float t = v - 1.f; ds += t * t; }
        else        { os += v * v; }
    }
    if (p == 0 && tid < DD) {
        float t = mu_s[tid] - centers[k * DD + tid];
        mm = t * t;
    }

    #pragma unroll
    for (int off = 32; off > 0; off >>= 1) {
        ds += __shfl_down(ds, off);
        os += __shfl_down(os, off);
        mm += __shfl_down(mm, off);
    }
    __shared__ float rds[4], ros[4], rmm[4];
    __shared__ int is_last;
    if (lane == 0) { rds[w] = ds; ros[w] = os; rmm[w] = mm; }
    __syncthreads();
    if (tid == 0) {
        float DS = rds[0] + rds[1] + rds[2] + rds[3];
        float OS = ros[0] + ros[1] + ros[2] + ros[3];
        float MM = rmm[0] + rmm[1] + rmm[2] + rmm[3];
        const float bd = (float)BB * (float)DD;
        float2 mine;
        mine.x = wgt * MM / bd;
        mine.y = wgt * DS / bd + wgt * OS / (bd * (float)(DD - 1));
        spart[blockIdx.x] = mine;
        __threadfence();                       // release partial
        int old = atomicAdd(counter, 1);
        is_last = (old == RBLKS - 1);
    }
    __syncthreads();
    if (is_last) {
        __threadfence();                       // acquire all partials
        float2 v = (tid < RBLKS) ? spart[tid] : make_float2(0.f, 0.f);
        float a = v.x, b = v.y;
        #pragma unroll
        for (int off = 32; off > 0; off >>= 1) {
            a += __shfl_down(a, off);
            b += __shfl_down(b, off);
        }
        __shared__ float ra[4], rb[4];
        if (lane == 0) { ra[w] = a; rb[w] = b; }
        __syncthreads();
        if (tid == 0) {
            outscalars[0] = ra[0] + ra[1] + ra[2] + ra[3];
            outscalars[1] = rb[0] + rb[1] + rb[2] + rb[3];
        }
    }
}

// ---------------------------------------------------------------------------
extern "C" void kernel_launch(void* const* d_in, const int* in_sizes, int n_in,
                              void* d_out, int out_size, void* d_ws, size_t ws_size,
                              hipStream_t stream) {
    const float* x = (const float*)d_in[0];
    const float* centers = (const float*)d_in[1];
    float* out = (float*)d_out;
    float* outscalars = out + (size_t)BB * KK;

    char* ws = (char*)d_ws;
    size_t off = 0;
    float*  part     = (float*)(ws + off); off += (size_t)MAXITEMS * DD * DD * 4; // 12.6 MB
    float*  emp_part = (float*)(ws + off); off += (size_t)MAXITEMS * DD * 4;      // 96 KB
    int*    sorted   = (int*)  (ws + off); off += BB * 4;                         // 64 KB
    int*    assign   = (int*)  (ws + off); off += BB * 4;                         // 64 KB
    int*    bhist    = (int*)  (ws + off); off += 256 * KK * 4;                   // 64 KB
    int4*   items    = (int4*) (ws + off); off += 256 * 16;                       // 4 KB
    float*  cw       = (float*)(ws + off); off += 256;
    int*    itemcnt  = (int*)  (ws + off); off += 256;
    int*    ist      = (int*)  (ws + off); off += 256;
    int*    ien      = (int*)  (ws + off); off += 256;
    float2* spart    = (float2*)(ws + off); off += RBLKS * 8;                     // 2 KB
    int*    counter  = (int*)  (ws + off); off += 256;

    k_rows    <<<256, 256, 0, stream>>>(x, centers, out, assign, bhist, counter);
    k_scat    <<<256, 256, 0, stream>>>(assign, bhist, sorted, cw, items,
                                        itemcnt, ist, ien);
    k_seg     <<<MAXITEMS, 256, 0, stream>>>(x, sorted, items, itemcnt,
                                             part, emp_part);
    k_redfinal<<<RBLKS, 256, 0, stream>>>(part, emp_part, cw, centers, ist, ien,
                                          spart, counter, outscalars);
}